// Round 3
// baseline (783.837 us; speedup 1.0000x reference)
//
#include <hip/hip_runtime.h>

typedef __bf16 bf16x8 __attribute__((ext_vector_type(8)));
typedef float  f32x4  __attribute__((ext_vector_type(4)));
typedef unsigned short u16;

#define N_EMBD 768
#define T_LEN 1024
#define S_LEN 257
#define S_PAD 288
#define BATCH 8
#define NH 12
#define BH (BATCH*NH)
#define HD 64

__device__ __forceinline__ u16 f2b(float f){
  union{float f; unsigned u;} v; v.f=f;
  unsigned r=(v.u + 0x7fffu + ((v.u>>16)&1u))>>16;
  return (u16)r;
}
__device__ __forceinline__ float b2f(u16 h){
  union{unsigned u; float f;} v; v.u=((unsigned)h)<<16;
  return v.f;
}
__device__ __forceinline__ void gl_lds16(const void* g, void* l){
  __builtin_amdgcn_global_load_lds((const __attribute__((address_space(1))) void*)g,
                                   (__attribute__((address_space(3))) void*)l, 16, 0, 0);
}

// ------------- f32 -> bf16 convert (contiguous) ---------------------------
__global__ void cvt_f32_bf16(const float* __restrict__ in, u16* __restrict__ out, int n4){
  int i = blockIdx.x*256 + threadIdx.x;
  if(i < n4){
    float4 f = *(const float4*)&in[i*4];
    ushort4 u; u.x=f2b(f.x); u.y=f2b(f.y); u.z=f2b(f.z); u.w=f2b(f.w);
    *(ushort4*)&out[i*4] = u;
  }
}

// ------------- transpose+convert: in f32 (K,N) -> out bf16 (N,K) ----------
__global__ void transpose_f32_bf16(const float* __restrict__ in, u16* __restrict__ out,
                                   int K, int N){
  __shared__ u16 tile[64][68];
  int k0 = blockIdx.y*64, n0 = blockIdx.x*64;
  int tr = threadIdx.x>>4;        // 0..15
  int tc = (threadIdx.x&15)*4;    // 0..60
#pragma unroll
  for(int i=0;i<4;i++){
    float4 f = *(const float4*)&in[(size_t)(k0+tr+i*16)*N + n0 + tc];
    tile[tr+i*16][tc+0]=f2b(f.x); tile[tr+i*16][tc+1]=f2b(f.y);
    tile[tr+i*16][tc+2]=f2b(f.z); tile[tr+i*16][tc+3]=f2b(f.w);
  }
  __syncthreads();
#pragma unroll
  for(int i=0;i<4;i++){
    int n = n0+tr+i*16;
    ushort4 u;
    u.x=tile[tc+0][tr+i*16]; u.y=tile[tc+1][tr+i*16];
    u.z=tile[tc+2][tr+i*16]; u.w=tile[tc+3][tr+i*16];
    *(ushort4*)&out[(size_t)n*K + k0 + tc] = u;
  }
}

// ------------- layernorm: one wave per row of 768, f32 in -> bf16 out -----
__global__ void ln_kernel(const float* __restrict__ x, const float* __restrict__ g,
                          const float* __restrict__ bta, u16* __restrict__ out){
  int row  = blockIdx.x*4 + (threadIdx.x>>6);
  int lane = threadIdx.x&63;
  size_t base = (size_t)row*N_EMBD;
  float v[12];
#pragma unroll
  for(int p=0;p<3;p++){
    int col = p*256 + lane*4;
    float4 f = *(const float4*)&x[base+col];
    v[p*4]=f.x; v[p*4+1]=f.y; v[p*4+2]=f.z; v[p*4+3]=f.w;
  }
  float s=0.f, s2=0.f;
#pragma unroll
  for(int i=0;i<12;i++){ s+=v[i]; s2+=v[i]*v[i]; }
#pragma unroll
  for(int off=1; off<64; off<<=1){ s += __shfl_xor(s,off); s2 += __shfl_xor(s2,off); }
  float mean = s*(1.f/N_EMBD);
  float var  = s2*(1.f/N_EMBD) - mean*mean;
  float rstd = rsqrtf(var + 1e-5f);
#pragma unroll
  for(int p=0;p<3;p++){
    int col = p*256 + lane*4;
#pragma unroll
    for(int j=0;j<4;j++){
      out[base+col+j] = f2b((v[p*4+j]-mean)*rstd*g[col+j] + bta[col+j]);
    }
  }
}

// ---------------- GEMM: C = A(M,K) @ Wt(N,K)^T + bias, fused epilogues ----
enum { M_QKV_SELF=0, M_Q_CROSS=1, M_KV_CROSS=2, M_RESID_F32=3,
       M_RESID_INPLACE=4, M_GELU=5, M_RESID_OUT=6 };

template<int MODE>
__global__ void gemm_bt(const u16* __restrict__ A, const u16* __restrict__ Wt,
                        const float* __restrict__ bias,
                        void* out0, void* out1, void* out2, const void* resid,
                        int M, int K){
  __shared__ u16 As[128*32];
  __shared__ u16 Bs[128*32];
  int tid=threadIdx.x, wave=tid>>6, lane=tid&63;
  int m0=blockIdx.y*128, n0=blockIdx.x*128;
  int wm=(wave>>1)*64, wn=(wave&1)*64;
  int lrow=lane&15, quad=lane>>4;
  f32x4 acc[4][4];
  f32x4 z = {0.f,0.f,0.f,0.f};
#pragma unroll
  for(int i=0;i<4;i++)
#pragma unroll
    for(int j=0;j<4;j++) acc[i][j]=z;

  int srow  = lane>>2;        // 0..15
  int schunk= (lane&3)*8;     // element offset
  int arow0 = wave*16 + srow;
  int arow1 = 64 + wave*16 + srow;

  for(int k0=0;k0<K;k0+=32){
    int ga0 = min(m0+arow0, M-1), ga1 = min(m0+arow1, M-1);
    gl_lds16(A  + (size_t)ga0*K + k0 + schunk, &As[(wave*16)*32]);
    gl_lds16(A  + (size_t)ga1*K + k0 + schunk, &As[(64+wave*16)*32]);
    gl_lds16(Wt + (size_t)(n0+arow0)*K + k0 + schunk, &Bs[(wave*16)*32]);
    gl_lds16(Wt + (size_t)(n0+arow1)*K + k0 + schunk, &Bs[(64+wave*16)*32]);
    __syncthreads();
    bf16x8 af[4], bfr[4];
#pragma unroll
    for(int i=0;i<4;i++){
      af[i]  = *(const bf16x8*)&As[(wm + i*16 + lrow)*32 + quad*8];
      bfr[i] = *(const bf16x8*)&Bs[(wn + i*16 + lrow)*32 + quad*8];
    }
#pragma unroll
    for(int mi=0;mi<4;mi++)
#pragma unroll
      for(int ni=0;ni<4;ni++)
        acc[mi][ni] = __builtin_amdgcn_mfma_f32_16x16x32_bf16(af[mi], bfr[ni], acc[mi][ni], 0,0,0);
    __syncthreads();
  }

#pragma unroll
  for(int ni=0;ni<4;ni++){
    int n = n0 + wn + ni*16 + lrow;
    float bv = bias[n];
#pragma unroll
    for(int mi=0;mi<4;mi++){
#pragma unroll
      for(int r=0;r<4;r++){
        int m = m0 + wm + mi*16 + quad*4 + r;
        if(m >= M) continue;
        float c = acc[mi][ni][r] + bv;
        if constexpr (MODE==M_QKV_SELF){
          int b=m>>10, t=m&1023;
          int part=n/768, nn=n-part*768;
          int hh=nn>>6, dd=nn&63;
          size_t bh=(size_t)(b*NH+hh);
          u16 vv=f2b(c);
          if(part==0)      ((u16*)out0)[(bh*T_LEN+t)*HD+dd]=vv;
          else if(part==1) ((u16*)out1)[(bh*T_LEN+t)*HD+dd]=vv;
          else             ((u16*)out2)[(bh*HD+dd)*T_LEN+t]=vv;
        } else if constexpr (MODE==M_Q_CROSS){
          int b=m>>10, t=m&1023;
          int hh=n>>6, dd=n&63;
          ((u16*)out0)[(((size_t)(b*NH+hh))*T_LEN+t)*HD+dd]=f2b(c);
        } else if constexpr (MODE==M_KV_CROSS){
          int b=m/S_LEN, s=m-b*S_LEN;
          int part=n/768, nn=n-part*768;
          int hh=nn>>6, dd=nn&63;
          size_t bh=(size_t)(b*NH+hh);
          u16 vv=f2b(c);
          if(part==0) ((u16*)out0)[(bh*S_PAD+s)*HD+dd]=vv;
          else        ((u16*)out1)[(bh*HD+dd)*S_PAD+s]=vv;
        } else if constexpr (MODE==M_RESID_F32){
          const float* x=(const float*)resid;
          ((float*)out0)[(size_t)m*768+n]=x[(size_t)m*768+n]+c;
        } else if constexpr (MODE==M_RESID_INPLACE){
          ((float*)out0)[(size_t)m*768+n]+=c;
        } else if constexpr (MODE==M_GELU){
          float u=c;
          float th=tanhf(0.7978845608028654f*(u+0.044715f*u*u*u));
          ((u16*)out0)[(size_t)m*3072+n]=f2b(0.5f*u*(1.f+th));
        } else { // M_RESID_OUT -> float32 output
          const float* x=(const float*)resid;
          ((float*)out0)[(size_t)m*768+n]=x[(size_t)m*768+n]+c;
        }
      }
    }
  }
}

// ---------------- flash attention: one wave per 16 Q rows -----------------
// Q: [BH][1024][64], K: [BH][Spad][64], V: [BH][64][Spad], O: [B][T][768] bf16
template<bool CAUSAL>
__global__ void flash_attn(const u16* __restrict__ Q, const u16* __restrict__ Kk,
                           const u16* __restrict__ V, u16* __restrict__ O,
                           int Skey, int Spad){
  __shared__ u16 Plds[4][16][40];
  int bh=blockIdx.y, b=bh/NH, hh=bh-b*NH;
  int wave=threadIdx.x>>6, lane=threadIdx.x&63;
  int lrow=lane&15, quad=lane>>4;
  const u16* Qp=Q+(size_t)bh*T_LEN*HD;
  const u16* Kp=Kk+(size_t)bh*Spad*HD;
  const u16* Vp=V+(size_t)bh*HD*Spad;
  u16* Op=O+(size_t)b*T_LEN*N_EMBD+hh*HD;
  int q0=blockIdx.x*64+wave*16;

  bf16x8 aq0=*(const bf16x8*)&Qp[(size_t)(q0+lrow)*HD + quad*8];
  bf16x8 aq1=*(const bf16x8*)&Qp[(size_t)(q0+lrow)*HD + 32 + quad*8];

  f32x4 oacc[4];
  f32x4 z={0.f,0.f,0.f,0.f};
#pragma unroll
  for(int i=0;i<4;i++) oacc[i]=z;
  float mrow[4], lsum[4];
#pragma unroll
  for(int r=0;r<4;r++){ mrow[r]=-1e30f; lsum[r]=0.f; }

  int kend = CAUSAL ? (q0+16) : Skey;
  for(int kt=0; kt<kend; kt+=32){
    f32x4 s0=z, s1=z;
    bf16x8 bk;
    bk=*(const bf16x8*)&Kp[(size_t)(kt+lrow)*HD + quad*8];        s0=__builtin_amdgcn_mfma_f32_16x16x32_bf16(aq0,bk,s0,0,0,0);
    bk=*(const bf16x8*)&Kp[(size_t)(kt+lrow)*HD + 32 + quad*8];   s0=__builtin_amdgcn_mfma_f32_16x16x32_bf16(aq1,bk,s0,0,0,0);
    bk=*(const bf16x8*)&Kp[(size_t)(kt+16+lrow)*HD + quad*8];     s1=__builtin_amdgcn_mfma_f32_16x16x32_bf16(aq0,bk,s1,0,0,0);
    bk=*(const bf16x8*)&Kp[(size_t)(kt+16+lrow)*HD + 32 + quad*8];s1=__builtin_amdgcn_mfma_f32_16x16x32_bf16(aq1,bk,s1,0,0,0);
    int key0=kt+lrow, key1=kt+16+lrow;
#pragma unroll
    for(int r=0;r<4;r++){
      int q=q0+quad*4+r;
      float v0=s0[r]*0.125f, v1=s1[r]*0.125f;
      bool msk0 = CAUSAL ? (key0>q) : (key0>=Skey);
      bool msk1 = CAUSAL ? (key1>q) : (key1>=Skey);
      if(msk0) v0=-1e30f;
      if(msk1) v1=-1e30f;
      float mx=fmaxf(v0,v1);
#pragma unroll
      for(int off=1; off<16; off<<=1) mx=fmaxf(mx,__shfl_xor(mx,off));
      float mnew=fmaxf(mrow[r],mx);
      float alpha=__expf(mrow[r]-mnew);
      float p0=__expf(v0-mnew), p1=__expf(v1-mnew);
      float rs=p0+p1;
#pragma unroll
      for(int off=1; off<16; off<<=1) rs+=__shfl_xor(rs,off);
      lsum[r]=lsum[r]*alpha+rs; mrow[r]=mnew;
      oacc[0][r]*=alpha; oacc[1][r]*=alpha; oacc[2][r]*=alpha; oacc[3][r]*=alpha;
      Plds[wave][quad*4+r][lrow]    = f2b(p0);
      Plds[wave][quad*4+r][16+lrow] = f2b(p1);
    }
    bf16x8 ap=*(const bf16x8*)&Plds[wave][lrow][quad*8];
#pragma unroll
    for(int dt=0;dt<4;dt++){
      bf16x8 bv=*(const bf16x8*)&Vp[(size_t)(dt*16+lrow)*Spad + kt + quad*8];
      oacc[dt]=__builtin_amdgcn_mfma_f32_16x16x32_bf16(ap,bv,oacc[dt],0,0,0);
    }
  }
#pragma unroll
  for(int dt=0;dt<4;dt++)
#pragma unroll
    for(int r=0;r<4;r++){
      int q=q0+quad*4+r;
      Op[(size_t)q*N_EMBD + dt*16 + lrow]=f2b(oacc[dt][r]/lsum[r]);
    }
}

// ---------------------------------------------------------------------------
extern "C" void kernel_launch(void* const* d_in, const int* in_sizes, int n_in,
                              void* d_out, int out_size, void* d_ws, size_t ws_size,
                              hipStream_t stream){
  const float* x_in   =(const float*)d_in[0];
  const float* enc    =(const float*)d_in[1];
  const float* ln1_g  =(const float*)d_in[2];
  const float* ln1_b  =(const float*)d_in[3];
  const float* ln2_g  =(const float*)d_in[4];
  const float* ln2_b  =(const float*)d_in[5];
  const float* ln3_g  =(const float*)d_in[6];
  const float* ln3_b  =(const float*)d_in[7];
  const float* attn_w =(const float*)d_in[8];
  const float* attn_b =(const float*)d_in[9];
  const float* attn_pw=(const float*)d_in[10];
  const float* attn_pb=(const float*)d_in[11];
  const float* cross_w=(const float*)d_in[12];
  const float* cross_b=(const float*)d_in[13];
  const float* cross_pw=(const float*)d_in[14];
  const float* cross_pb=(const float*)d_in[15];
  const float* fc_w   =(const float*)d_in[16];
  const float* fc_b   =(const float*)d_in[17];
  const float* proj_w =(const float*)d_in[18];
  const float* proj_b =(const float*)d_in[19];

  char* ws=(char*)d_ws;
  u16*  attn_wT  =(u16*)(ws + 0);           // 2304x768 bf16
  u16*  cross_wT =(u16*)(ws + 3538944);     // 2304x768
  u16*  attn_pwT =(u16*)(ws + 7077888);     // 768x768
  u16*  cross_pwT=(u16*)(ws + 8257536);     // 768x768
  u16*  fc_wT    =(u16*)(ws + 9437184);     // 3072x768
  u16*  proj_wT  =(u16*)(ws + 14155776);    // 768x3072
  float* xcur    =(float*)(ws + 18874368);  // 8192x768 f32
  u16*  hbuf     =(u16*)(ws + 44040192);    // 8192x768 bf16 (LN out / attn out)
  u16*  Qs       =(u16*)(ws + 56623104);    // 96x1024x64
  u16*  Ks       =(u16*)(ws + 69206016);
  u16*  Vst      =(u16*)(ws + 81788928);
  u16*  Qc       =(u16*)(ws + 94371840);
  u16*  hf       =(u16*)(ws + 56623104);    // 8192x3072, reuses Qs..Qc (MLP phase)
  u16*  Kc       =(u16*)(ws + 106954752);   // 96x288x64
  u16*  Vct      =(u16*)(ws + 110493696);   // 96x64x288
  u16*  enc_bf   =(u16*)(ws + 114032640);   // 2056x768 bf16

  dim3 blk(256);
  // input conversions / weight transposes (f32 -> bf16)
  cvt_f32_bf16<<<1542,blk,0,stream>>>(enc, enc_bf, 394752);
  transpose_f32_bf16<<<dim3(2304/64, 768/64),blk,0,stream>>>(attn_w,  attn_wT,  768, 2304);
  transpose_f32_bf16<<<dim3(2304/64, 768/64),blk,0,stream>>>(cross_w, cross_wT, 768, 2304);
  transpose_f32_bf16<<<dim3( 768/64, 768/64),blk,0,stream>>>(attn_pw, attn_pwT, 768, 768);
  transpose_f32_bf16<<<dim3( 768/64, 768/64),blk,0,stream>>>(cross_pw,cross_pwT,768, 768);
  transpose_f32_bf16<<<dim3(3072/64, 768/64),blk,0,stream>>>(fc_w,    fc_wT,    768, 3072);
  transpose_f32_bf16<<<dim3( 768/64,3072/64),blk,0,stream>>>(proj_w,  proj_wT,  3072,768);

  // self-attention
  ln_kernel<<<2048,blk,0,stream>>>(x_in, ln1_g, ln1_b, hbuf);
  gemm_bt<M_QKV_SELF><<<dim3(18,64),blk,0,stream>>>(hbuf, attn_wT, attn_b,
      Qs, Ks, Vst, nullptr, 8192, 768);
  flash_attn<true><<<dim3(16,96),blk,0,stream>>>(Qs, Ks, Vst, hbuf, 1024, 1024);
  gemm_bt<M_RESID_F32><<<dim3(6,64),blk,0,stream>>>(hbuf, attn_pwT, attn_pb,
      xcur, nullptr, nullptr, x_in, 8192, 768);

  // cross-attention
  ln_kernel<<<2048,blk,0,stream>>>(xcur, ln2_g, ln2_b, hbuf);
  gemm_bt<M_Q_CROSS><<<dim3(6,64),blk,0,stream>>>(hbuf, cross_wT, cross_b,
      Qc, nullptr, nullptr, nullptr, 8192, 768);
  gemm_bt<M_KV_CROSS><<<dim3(12,17),blk,0,stream>>>(enc_bf, cross_wT + 768*768,
      cross_b + 768, Kc, Vct, nullptr, nullptr, 2056, 768);
  flash_attn<false><<<dim3(16,96),blk,0,stream>>>(Qc, Kc, Vct, hbuf, S_LEN, S_PAD);
  gemm_bt<M_RESID_INPLACE><<<dim3(6,64),blk,0,stream>>>(hbuf, cross_pwT, cross_pb,
      xcur, nullptr, nullptr, nullptr, 8192, 768);

  // MLP
  ln_kernel<<<2048,blk,0,stream>>>(xcur, ln3_g, ln3_b, hbuf);
  gemm_bt<M_GELU><<<dim3(24,64),blk,0,stream>>>(hbuf, fc_wT, fc_b,
      hf, nullptr, nullptr, nullptr, 8192, 768);
  gemm_bt<M_RESID_OUT><<<dim3(6,64),blk,0,stream>>>(hf, proj_wT, proj_b,
      d_out, nullptr, nullptr, xcur, 8192, 3072);
}